// Round 1
// baseline (1373.136 us; speedup 1.0000x reference)
//
#include <hip/hip_runtime.h>

// GCN, 2 layers, feature dims 1 -> 16 -> 2.
// Key simplification: layer-1 edge aggregation is SCALAR (in-dim = 1):
//   s[c] = sum_e norm_e * x[row_e]  (+ self-loop term dis[c]^2 * x[c])
//   h1[c] = relu(s[c]*W1 + b1)   (16-vec, per node)
//   h2[c] = W2 @ h1[c]           (2-vec, per node)
//   out[c] = b2 + dis[c]^2*h2[c] + sum_e norm_e * h2[row_e]   (2 atomics/edge)

static constexpr int BLOCK = 256;

__global__ void k_init_deg(float* __restrict__ deg, int n) {
    int i = blockIdx.x * blockDim.x + threadIdx.x;
    if (i < n) deg[i] = 1.0f;  // self-loop contributes 1 to every node's degree
}

__global__ void k_deg(const int* __restrict__ col, float* __restrict__ deg, int e) {
    int i = blockIdx.x * blockDim.x + threadIdx.x;
    if (i < e) atomicAdd(&deg[col[i]], 1.0f);
}

// dis = rsqrt(deg) (deg >= 1 always, self-loop); seed s with self-loop term.
__global__ void k_dis_self(const float* __restrict__ x, float* __restrict__ deg_dis,
                           float* __restrict__ s, int n) {
    int i = blockIdx.x * blockDim.x + threadIdx.x;
    if (i < n) {
        float di = rsqrtf(deg_dis[i]);
        deg_dis[i] = di;
        s[i] = di * di * x[i];
    }
}

__global__ void k_agg1(const int* __restrict__ row, const int* __restrict__ col,
                       const float* __restrict__ dis, const float* __restrict__ x,
                       float* __restrict__ s, int e) {
    int i = blockIdx.x * blockDim.x + threadIdx.x;
    if (i < e) {
        int r = row[i], c = col[i];
        atomicAdd(&s[c], dis[r] * dis[c] * x[r]);
    }
}

// Per-node MLP: h1 = relu(s*W1+b1); h2 = W2@h1. Also init out with bias + self-loop.
__global__ void k_mlp(const float* __restrict__ s, const float* __restrict__ dis,
                      const float* __restrict__ W1, const float* __restrict__ b1,
                      const float* __restrict__ W2, const float* __restrict__ b2,
                      float* __restrict__ h2, float* __restrict__ out, int n) {
    int i = blockIdx.x * blockDim.x + threadIdx.x;
    if (i < n) {
        float sv = s[i];
        float a0 = 0.0f, a1 = 0.0f;
#pragma unroll
        for (int j = 0; j < 16; ++j) {
            float h1 = fmaxf(sv * W1[j] + b1[j], 0.0f);
            a0 = fmaf(W2[j],      h1, a0);   // W2[0][j]
            a1 = fmaf(W2[16 + j], h1, a1);   // W2[1][j]
        }
        h2[2 * i]     = a0;
        h2[2 * i + 1] = a1;
        float d2 = dis[i] * dis[i];
        out[2 * i]     = b2[0] + d2 * a0;
        out[2 * i + 1] = b2[1] + d2 * a1;
    }
}

__global__ void k_agg2(const int* __restrict__ row, const int* __restrict__ col,
                       const float* __restrict__ dis, const float* __restrict__ h2,
                       float* __restrict__ out, int e) {
    int i = blockIdx.x * blockDim.x + threadIdx.x;
    if (i < e) {
        int r = row[i], c = col[i];
        float nm = dis[r] * dis[c];
        float2 hv = *reinterpret_cast<const float2*>(&h2[2 * r]);
        atomicAdd(&out[2 * c],     nm * hv.x);
        atomicAdd(&out[2 * c + 1], nm * hv.y);
    }
}

extern "C" void kernel_launch(void* const* d_in, const int* in_sizes, int n_in,
                              void* d_out, int out_size, void* d_ws, size_t ws_size,
                              hipStream_t stream) {
    const float* x  = (const float*)d_in[0];
    const int*   ei = (const int*)d_in[1];   // [2, E] row-major: row then col
    const float* W1 = (const float*)d_in[2];
    const float* b1 = (const float*)d_in[3];
    const float* W2 = (const float*)d_in[4];
    const float* b2 = (const float*)d_in[5];
    float* out = (float*)d_out;

    const int n = in_sizes[0];        // 100000 (x is [N,1])
    const int e = in_sizes[1] / 2;    // 6400000
    const int* row = ei;
    const int* col = ei + e;

    // Workspace layout (all re-initialized every call; ws is poisoned 0xAA):
    float* dis = (float*)d_ws;        // n floats: deg, then rsqrt(deg) in place
    float* s   = dis + n;             // n floats: layer-1 scalar aggregate
    float* h2  = s + n;               // 2n floats: per-node layer-2 pre-aggregation

    const int gn = (n + BLOCK - 1) / BLOCK;
    const int ge = (e + BLOCK - 1) / BLOCK;

    k_init_deg<<<gn, BLOCK, 0, stream>>>(dis, n);
    k_deg<<<ge, BLOCK, 0, stream>>>(col, dis, e);
    k_dis_self<<<gn, BLOCK, 0, stream>>>(x, dis, s, n);
    k_agg1<<<ge, BLOCK, 0, stream>>>(row, col, dis, x, s, e);
    k_mlp<<<gn, BLOCK, 0, stream>>>(s, dis, W1, b1, W2, b2, h2, out, n);
    k_agg2<<<ge, BLOCK, 0, stream>>>(row, col, dis, h2, out, e);
}

// Round 2
// 640.852 us; speedup vs baseline: 2.1427x; 2.1427x over previous
//
#include <hip/hip_runtime.h>

// GCN 2-layer, dims 1 -> 16 -> 2, N=100K nodes, E=6.4M edges.
//
// R1 lesson (rocprof): device-scope float atomics cost one 32B fabric packet
// each (~20 G/s ceiling; k_agg2 WRITE_SIZE=400MB for an 800KB output). So R2
// replaces ALL global atomics with LDS-privatized histograms + plain-write
// partials + a tree reduce:
//   grid = R node-ranges x B edge-chunks. Each block keeps bins for its node
//   range in LDS (<=50KB), scans its edge chunk (cols are LLC-resident, the
//   Rx re-read is absorbed by the 256MB L3), LDS-atomicAdd for in-range cols,
//   then flushes bins with coalesced plain writes to partials[b][*] in ws.
//   A reduce kernel sums partials over b — no fabric atomics at all.
//
// Algebra: dis = rsqrt(1 + indeg);  t[r] = dis[r]*x[r]
//   s[c]  = dis[c]*(sum_e t[row_e] + t[c])          (layer-1 scalar aggregate)
//   h2[c] = W2 @ relu(s[c]*W1 + b1);  u[c] = dis[c]*h2[c]   (float2)
//   out[c] = b2 + dis[c]*(sum_e u[row_e] + u[c])

static constexpr int R1P = 8,  BINS1 = 12504;  // >= ceil(100000/8),  50.0 KB
static constexpr int R2P = 16, BINS2 = 6256;   // >= ceil(100000/16), 50.0 KB float2

__global__ __launch_bounds__(1024) void k_deg_priv(const int* __restrict__ col,
        float* __restrict__ P, int n, int e, int B) {
    __shared__ int h[BINS1];
    const int bins = (n + R1P - 1) / R1P;
    const int r = blockIdx.x % R1P, b = blockIdx.x / R1P;
    const int base = r * bins;
    const int cnt = min(bins, n - base);
    for (int j = threadIdx.x; j < cnt; j += 1024) h[j] = 0;
    __syncthreads();
    const int chunk = (e + B - 1) / B;
    const int lo = b * chunk, end = min(lo + chunk, e);
    for (int i = lo + threadIdx.x; i < end; i += 1024) {
        int c = col[i] - base;
        if ((unsigned)c < (unsigned)cnt) atomicAdd(&h[c], 1);
    }
    __syncthreads();
    float* Pb = P + (size_t)b * n + base;
    for (int j = threadIdx.x; j < cnt; j += 1024) Pb[j] = (float)h[j];
}

__global__ __launch_bounds__(1024) void k_agg1_priv(const int* __restrict__ row,
        const int* __restrict__ col, const float* __restrict__ t,
        float* __restrict__ P, int n, int e, int B) {
    __shared__ float h[BINS1];
    const int bins = (n + R1P - 1) / R1P;
    const int r = blockIdx.x % R1P, b = blockIdx.x / R1P;
    const int base = r * bins;
    const int cnt = min(bins, n - base);
    for (int j = threadIdx.x; j < cnt; j += 1024) h[j] = 0.0f;
    __syncthreads();
    const int chunk = (e + B - 1) / B;
    const int lo = b * chunk, end = min(lo + chunk, e);
    for (int i = lo + threadIdx.x; i < end; i += 1024) {
        int c = col[i] - base;
        if ((unsigned)c < (unsigned)cnt) atomicAdd(&h[c], t[row[i]]);
    }
    __syncthreads();
    float* Pb = P + (size_t)b * n + base;
    for (int j = threadIdx.x; j < cnt; j += 1024) Pb[j] = h[j];
}

__global__ __launch_bounds__(1024) void k_agg2_priv(const int* __restrict__ row,
        const int* __restrict__ col, const float2* __restrict__ u,
        float* __restrict__ P, int n, int e, int B) {
    __shared__ float h[2 * BINS2];
    const int bins = (n + R2P - 1) / R2P;
    const int r = blockIdx.x % R2P, b = blockIdx.x / R2P;
    const int base = r * bins;
    const int cnt = min(bins, n - base);
    for (int j = threadIdx.x; j < 2 * cnt; j += 1024) h[j] = 0.0f;
    __syncthreads();
    const int chunk = (e + B - 1) / B;
    const int lo = b * chunk, end = min(lo + chunk, e);
    for (int i = lo + threadIdx.x; i < end; i += 1024) {
        int c = col[i] - base;
        if ((unsigned)c < (unsigned)cnt) {
            float2 uv = u[row[i]];
            atomicAdd(&h[2 * c],     uv.x);
            atomicAdd(&h[2 * c + 1], uv.y);
        }
    }
    __syncthreads();
    float* Pb = P + (size_t)b * 2 * n + 2 * base;
    for (int j = threadIdx.x; j < 2 * cnt; j += 1024) Pb[j] = h[j];
}

// deg reduce: dis = rsqrt(1 + sum_b P), t = dis*x
__global__ void k_prep(const float* __restrict__ P, const float* __restrict__ x,
        float* __restrict__ dis, float* __restrict__ t, int n, int B) {
    int c = blockIdx.x * blockDim.x + threadIdx.x;
    if (c >= n) return;
    float s = 1.0f;
    for (int b = 0; b < B; ++b) s += P[(size_t)b * n + c];
    float di = rsqrtf(s);
    dis[c] = di;
    t[c] = di * x[c];
}

// layer-1 reduce + MLP: u[c] = dis[c] * (W2 @ relu(s*W1 + b1))
__global__ void k_mlp(const float* __restrict__ P, const float* __restrict__ dis,
        const float* __restrict__ t, const float* __restrict__ W1,
        const float* __restrict__ b1, const float* __restrict__ W2,
        float2* __restrict__ u, int n, int B) {
    int c = blockIdx.x * blockDim.x + threadIdx.x;
    if (c >= n) return;
    float S = 0.0f;
    for (int b = 0; b < B; ++b) S += P[(size_t)b * n + c];
    float di = dis[c];
    float s = di * (S + t[c]);
    float a0 = 0.0f, a1 = 0.0f;
#pragma unroll
    for (int j = 0; j < 16; ++j) {
        float hh = fmaxf(fmaf(s, W1[j], b1[j]), 0.0f);
        a0 = fmaf(W2[j],      hh, a0);
        a1 = fmaf(W2[16 + j], hh, a1);
    }
    u[c] = make_float2(di * a0, di * a1);
}

// layer-2 reduce: out[2c+k] = b2[k] + dis[c]*(S[k] + u[2c+k])
__global__ void k_outk(const float* __restrict__ P, const float* __restrict__ dis,
        const float* __restrict__ u, const float* __restrict__ b2,
        float* __restrict__ out, int n, int B) {
    int tid = blockIdx.x * blockDim.x + threadIdx.x;
    if (tid >= 2 * n) return;
    float S = 0.0f;
    for (int b = 0; b < B; ++b) S += P[(size_t)b * 2 * n + tid];
    int c = tid >> 1;
    out[tid] = b2[tid & 1] + dis[c] * (S + u[tid]);
}

// ---------- R1 fallback path (fabric atomics) if ws is too small ----------
static constexpr int BLOCK = 256;
__global__ void f_init_deg(float* deg, int n) {
    int i = blockIdx.x * blockDim.x + threadIdx.x;
    if (i < n) deg[i] = 1.0f;
}
__global__ void f_deg(const int* col, float* deg, int e) {
    int i = blockIdx.x * blockDim.x + threadIdx.x;
    if (i < e) atomicAdd(&deg[col[i]], 1.0f);
}
__global__ void f_dis_self(const float* x, float* deg_dis, float* s, int n) {
    int i = blockIdx.x * blockDim.x + threadIdx.x;
    if (i < n) { float di = rsqrtf(deg_dis[i]); deg_dis[i] = di; s[i] = di * di * x[i]; }
}
__global__ void f_agg1(const int* row, const int* col, const float* dis,
                       const float* x, float* s, int e) {
    int i = blockIdx.x * blockDim.x + threadIdx.x;
    if (i < e) { int r = row[i], c = col[i]; atomicAdd(&s[c], dis[r] * dis[c] * x[r]); }
}
__global__ void f_mlp(const float* s, const float* dis, const float* W1,
                      const float* b1, const float* W2, const float* b2,
                      float* h2, float* out, int n) {
    int i = blockIdx.x * blockDim.x + threadIdx.x;
    if (i < n) {
        float sv = s[i], a0 = 0.0f, a1 = 0.0f;
#pragma unroll
        for (int j = 0; j < 16; ++j) {
            float h1 = fmaxf(sv * W1[j] + b1[j], 0.0f);
            a0 = fmaf(W2[j], h1, a0); a1 = fmaf(W2[16 + j], h1, a1);
        }
        h2[2 * i] = a0; h2[2 * i + 1] = a1;
        float d2 = dis[i] * dis[i];
        out[2 * i] = b2[0] + d2 * a0; out[2 * i + 1] = b2[1] + d2 * a1;
    }
}
__global__ void f_agg2(const int* row, const int* col, const float* dis,
                       const float* h2, float* out, int e) {
    int i = blockIdx.x * blockDim.x + threadIdx.x;
    if (i < e) {
        int r = row[i], c = col[i];
        float nm = dis[r] * dis[c];
        float2 hv = *reinterpret_cast<const float2*>(&h2[2 * r]);
        atomicAdd(&out[2 * c], nm * hv.x);
        atomicAdd(&out[2 * c + 1], nm * hv.y);
    }
}
// --------------------------------------------------------------------------

extern "C" void kernel_launch(void* const* d_in, const int* in_sizes, int n_in,
                              void* d_out, int out_size, void* d_ws, size_t ws_size,
                              hipStream_t stream) {
    const float* x  = (const float*)d_in[0];
    const int*   ei = (const int*)d_in[1];
    const float* W1 = (const float*)d_in[2];
    const float* b1 = (const float*)d_in[3];
    const float* W2 = (const float*)d_in[4];
    const float* b2 = (const float*)d_in[5];
    float* out = (float*)d_out;

    const int n = in_sizes[0];
    const int e = in_sizes[1] / 2;
    const int* row = ei;
    const int* col = ei + e;

    const int B1 = 32;   // chunks for deg/agg1 (R1P=8  ranges -> 256 blocks)
    const int B2 = 16;   // chunks for agg2     (R2P=16 ranges -> 256 blocks)

    // ws: dis[n] | t[n] | u[2n] | P[max(B1*n, B2*2n)]
    size_t pfloats = (size_t)B1 * n > (size_t)B2 * 2 * n ? (size_t)B1 * n
                                                         : (size_t)B2 * 2 * n;
    size_t need = ((size_t)4 * n + pfloats) * sizeof(float);

    if (ws_size < need) {  // fallback: R1 atomic path (needs only 4n floats)
        float* dis = (float*)d_ws; float* s = dis + n; float* h2 = s + n;
        const int gn = (n + BLOCK - 1) / BLOCK, ge = (e + BLOCK - 1) / BLOCK;
        f_init_deg<<<gn, BLOCK, 0, stream>>>(dis, n);
        f_deg<<<ge, BLOCK, 0, stream>>>(col, dis, e);
        f_dis_self<<<gn, BLOCK, 0, stream>>>(x, dis, s, n);
        f_agg1<<<ge, BLOCK, 0, stream>>>(row, col, dis, x, s, e);
        f_mlp<<<gn, BLOCK, 0, stream>>>(s, dis, W1, b1, W2, b2, h2, out, n);
        f_agg2<<<ge, BLOCK, 0, stream>>>(row, col, dis, h2, out, e);
        return;
    }

    float*  dis = (float*)d_ws;
    float*  t   = dis + n;
    float2* u   = (float2*)(t + n);
    float*  P   = (float*)(u + n);

    const int gn  = (n + 255) / 256;
    const int gn2 = (2 * n + 255) / 256;

    k_deg_priv <<<R1P * B1, 1024, 0, stream>>>(col, P, n, e, B1);
    k_prep     <<<gn, 256, 0, stream>>>(P, x, dis, t, n, B1);
    k_agg1_priv<<<R1P * B1, 1024, 0, stream>>>(row, col, t, P, n, e, B1);
    k_mlp      <<<gn, 256, 0, stream>>>(P, dis, t, W1, b1, W2, u, n, B1);
    k_agg2_priv<<<R2P * B2, 1024, 0, stream>>>(row, col, u, P, n, e, B2);
    k_outk     <<<gn2, 256, 0, stream>>>(P, dis, (const float*)u, b2, out, n, B2);
}

// Round 3
// 353.008 us; speedup vs baseline: 3.8898x; 1.8154x over previous
//
#include <hip/hip_runtime.h>

// GCN 2-layer, dims 1 -> 16 -> 2, N=100K, E=6.4M.
//
// R1 lesson: fabric float atomics = 32B packet each, ~20 G/s -> 1.3 ms.
// R2 lesson: LDS-privatized ranges kill atomics but pay an Rx (16x) re-read
//            of the edge stream (FETCH 202MB on an 800KB output). 641 us.
// R3: counting-sort edges into col-buckets of BW=128 nodes ONCE (packed
//     (row<<7|col&127) int per edge), then deg/agg1/agg2 each read every
//     edge exactly once with 128-entry LDS bins. No global atomics, no
//     redundant edge reads. ~185MB total HBM traffic.
//
// Algebra: dis = rsqrt(1+indeg); t = dis*x
//   s[c]  = dis[c]*(sum_{e->c} t[row] + t[c])
//   u[c]  = dis[c]*(W2 @ relu(s[c]*W1 + b1))          (float2)
//   out[c]= b2 + dis[c]*(sum_{e->c} u[row] + u[c])

static constexpr int NB   = 512;   // partition blocks (hist/scatter grid)
static constexpr int BW   = 128;   // nodes per bucket (pow2)
static constexpr int BSH  = 7;     // log2(BW)
static constexpr int MAXK = 1024;  // max buckets in LDS (n <= 131072)

// ---- 1) per-block bucket histogram: H[k*NB + b] = count ----
__global__ __launch_bounds__(256) void k_hist(const int* __restrict__ col,
        int* __restrict__ H, int e, int NK) {
    __shared__ int h[MAXK];
    for (int j = threadIdx.x; j < NK; j += 256) h[j] = 0;
    __syncthreads();
    const int chunk = (e + NB - 1) / NB;
    const int lo = blockIdx.x * chunk, end = min(lo + chunk, e);
    for (int i = lo + threadIdx.x; i < end; i += 256)
        atomicAdd(&h[col[i] >> BSH], 1);
    __syncthreads();
    for (int j = threadIdx.x; j < NK; j += 256)
        H[(size_t)j * NB + blockIdx.x] = h[j];
}

// ---- 2) exclusive scan of H (flat, length M = NK*NB), 3 tiny kernels ----
__global__ __launch_bounds__(1024) void k_scanA(int* __restrict__ H,
        int* __restrict__ totals, int M) {
    __shared__ int s[1024];
    const int tid = threadIdx.x, idx = blockIdx.x * 1024 + tid;
    int v = (idx < M) ? H[idx] : 0;
    s[tid] = v;
    __syncthreads();
    for (int off = 1; off < 1024; off <<= 1) {
        int tv = (tid >= off) ? s[tid - off] : 0;
        __syncthreads();
        s[tid] += tv;
        __syncthreads();
    }
    if (idx < M) H[idx] = s[tid] - v;          // exclusive
    if (tid == 1023) totals[blockIdx.x] = s[1023];
}

__global__ __launch_bounds__(1024) void k_scanB(const int* __restrict__ totals,
        int* __restrict__ tscan, int G) {
    __shared__ int s[1024];
    const int tid = threadIdx.x;
    int v = (tid < G) ? totals[tid] : 0;
    s[tid] = v;
    __syncthreads();
    for (int off = 1; off < 1024; off <<= 1) {
        int tv = (tid >= off) ? s[tid - off] : 0;
        __syncthreads();
        s[tid] += tv;
        __syncthreads();
    }
    if (tid < G) tscan[tid] = s[tid] - v;
}

__global__ __launch_bounds__(1024) void k_scanC(int* __restrict__ H,
        const int* __restrict__ tscan, int M) {
    int idx = blockIdx.x * 1024 + threadIdx.x;
    if (idx < M) H[idx] += tscan[blockIdx.x];
}

// ---- 3) scatter edges into bucketed packed array P ----
__global__ __launch_bounds__(256) void k_scatter(const int* __restrict__ row,
        const int* __restrict__ col, const int* __restrict__ H,
        int* __restrict__ P, int e, int NK) {
    __shared__ int cur[MAXK];
    const int b = blockIdx.x;
    for (int j = threadIdx.x; j < NK; j += 256) cur[j] = H[(size_t)j * NB + b];
    __syncthreads();
    const int chunk = (e + NB - 1) / NB;
    const int lo = b * chunk, end = min(lo + chunk, e);
    for (int i = lo + threadIdx.x; i < end; i += 256) {
        int c = col[i], r = row[i];
        int pos = atomicAdd(&cur[c >> BSH], 1);
        P[pos] = (r << BSH) | (c & (BW - 1));
    }
}

// ---- 4) deg + prep: dis = rsqrt(1+indeg), t = dis*x ----
__global__ __launch_bounds__(256) void k_degprep(const int* __restrict__ P,
        const int* __restrict__ H, const float* __restrict__ x,
        float* __restrict__ dis, float* __restrict__ t, int n, int e, int NK) {
    __shared__ int bin[BW];
    const int k = blockIdx.x;
    if (threadIdx.x < BW) bin[threadIdx.x] = 0;
    __syncthreads();
    const int start = H[(size_t)k * NB];
    const int end = (k + 1 < NK) ? H[(size_t)(k + 1) * NB] : e;
    for (int i = start + threadIdx.x; i < end; i += 256)
        atomicAdd(&bin[P[i] & (BW - 1)], 1);
    __syncthreads();
    const int c = k * BW + threadIdx.x;
    if (threadIdx.x < BW && c < n) {
        float di = rsqrtf(1.0f + (float)bin[threadIdx.x]);
        dis[c] = di;
        t[c] = di * x[c];
    }
}

// ---- 5) layer-1 aggregate + MLP fused: u = dis*(W2 @ relu(s*W1+b1)) ----
__global__ __launch_bounds__(256) void k_agg1mlp(const int* __restrict__ P,
        const int* __restrict__ H, const float* __restrict__ dis,
        const float* __restrict__ t, const float* __restrict__ W1,
        const float* __restrict__ b1, const float* __restrict__ W2,
        float2* __restrict__ u, int n, int e, int NK) {
    __shared__ float bin[BW];
    const int k = blockIdx.x;
    if (threadIdx.x < BW) bin[threadIdx.x] = 0.0f;
    __syncthreads();
    const int start = H[(size_t)k * NB];
    const int end = (k + 1 < NK) ? H[(size_t)(k + 1) * NB] : e;
    for (int i = start + threadIdx.x; i < end; i += 256) {
        int p = P[i];
        atomicAdd(&bin[p & (BW - 1)], t[p >> BSH]);
    }
    __syncthreads();
    const int c = k * BW + threadIdx.x;
    if (threadIdx.x < BW && c < n) {
        float di = dis[c];
        float s = di * (bin[threadIdx.x] + t[c]);
        float a0 = 0.0f, a1 = 0.0f;
#pragma unroll
        for (int j = 0; j < 16; ++j) {
            float hh = fmaxf(fmaf(s, W1[j], b1[j]), 0.0f);
            a0 = fmaf(W2[j],      hh, a0);
            a1 = fmaf(W2[16 + j], hh, a1);
        }
        u[c] = make_float2(di * a0, di * a1);
    }
}

// ---- 6) layer-2 aggregate + epilogue: out = b2 + dis*(agg + u_self) ----
__global__ __launch_bounds__(256) void k_agg2out(const int* __restrict__ P,
        const int* __restrict__ H, const float* __restrict__ dis,
        const float2* __restrict__ u, const float* __restrict__ b2,
        float2* __restrict__ out, int n, int e, int NK) {
    __shared__ float bin[2 * BW];
    for (int j = threadIdx.x; j < 2 * BW; j += 256) bin[j] = 0.0f;
    __syncthreads();
    const int k = blockIdx.x;
    const int start = H[(size_t)k * NB];
    const int end = (k + 1 < NK) ? H[(size_t)(k + 1) * NB] : e;
    for (int i = start + threadIdx.x; i < end; i += 256) {
        int p = P[i];
        float2 uv = u[p >> BSH];
        int cl = p & (BW - 1);
        atomicAdd(&bin[2 * cl],     uv.x);
        atomicAdd(&bin[2 * cl + 1], uv.y);
    }
    __syncthreads();
    const int c = k * BW + threadIdx.x;
    if (threadIdx.x < BW && c < n) {
        float di = dis[c];
        float2 uc = u[c];
        out[c] = make_float2(b2[0] + di * (bin[2 * threadIdx.x]     + uc.x),
                             b2[1] + di * (bin[2 * threadIdx.x + 1] + uc.y));
    }
}

// ---------- generic atomic fallback (correct for any n/e, slow) ----------
static constexpr int BLOCK = 256;
__global__ void f_init_deg(float* deg, int n) {
    int i = blockIdx.x * blockDim.x + threadIdx.x;
    if (i < n) deg[i] = 1.0f;
}
__global__ void f_deg(const int* col, float* deg, int e) {
    int i = blockIdx.x * blockDim.x + threadIdx.x;
    if (i < e) atomicAdd(&deg[col[i]], 1.0f);
}
__global__ void f_dis_self(const float* x, float* deg_dis, float* s, int n) {
    int i = blockIdx.x * blockDim.x + threadIdx.x;
    if (i < n) { float di = rsqrtf(deg_dis[i]); deg_dis[i] = di; s[i] = di * di * x[i]; }
}
__global__ void f_agg1(const int* row, const int* col, const float* dis,
                       const float* x, float* s, int e) {
    int i = blockIdx.x * blockDim.x + threadIdx.x;
    if (i < e) { int r = row[i], c = col[i]; atomicAdd(&s[c], dis[r] * dis[c] * x[r]); }
}
__global__ void f_mlp(const float* s, const float* dis, const float* W1,
                      const float* b1, const float* W2, const float* b2,
                      float* h2, float* out, int n) {
    int i = blockIdx.x * blockDim.x + threadIdx.x;
    if (i < n) {
        float sv = s[i], a0 = 0.0f, a1 = 0.0f;
#pragma unroll
        for (int j = 0; j < 16; ++j) {
            float h1 = fmaxf(sv * W1[j] + b1[j], 0.0f);
            a0 = fmaf(W2[j], h1, a0); a1 = fmaf(W2[16 + j], h1, a1);
        }
        h2[2 * i] = a0; h2[2 * i + 1] = a1;
        float d2 = dis[i] * dis[i];
        out[2 * i] = b2[0] + d2 * a0; out[2 * i + 1] = b2[1] + d2 * a1;
    }
}
__global__ void f_agg2(const int* row, const int* col, const float* dis,
                       const float* h2, float* out, int e) {
    int i = blockIdx.x * blockDim.x + threadIdx.x;
    if (i < e) {
        int r = row[i], c = col[i];
        float nm = dis[r] * dis[c];
        float2 hv = *reinterpret_cast<const float2*>(&h2[2 * r]);
        atomicAdd(&out[2 * c], nm * hv.x);
        atomicAdd(&out[2 * c + 1], nm * hv.y);
    }
}
// -------------------------------------------------------------------------

extern "C" void kernel_launch(void* const* d_in, const int* in_sizes, int n_in,
                              void* d_out, int out_size, void* d_ws, size_t ws_size,
                              hipStream_t stream) {
    const float* x  = (const float*)d_in[0];
    const int*   ei = (const int*)d_in[1];
    const float* W1 = (const float*)d_in[2];
    const float* b1 = (const float*)d_in[3];
    const float* W2 = (const float*)d_in[4];
    const float* b2 = (const float*)d_in[5];
    float* out = (float*)d_out;

    const int n = in_sizes[0];
    const int e = in_sizes[1] / 2;
    const int* row = ei;
    const int* col = ei + e;

    const int NK = (n + BW - 1) / BW;          // buckets
    const int M  = NK * NB;                    // scan length
    const int GS = (M + 1023) / 1024;          // scanA/C grid

    // ws: P[e] | H[M] | totals[1024] | tscan[1024] | dis[n] | t[n] | u[2n]
    size_t need = ((size_t)e + M + 2048 + 4 * (size_t)n) * 4;

    if (NK > MAXK || GS > 1024 || ws_size < need) {
        // generic fallback: fabric atomics (needs 4n floats)
        float* dis = (float*)d_ws; float* s = dis + n; float* h2 = s + n;
        const int gn = (n + BLOCK - 1) / BLOCK, ge = (e + BLOCK - 1) / BLOCK;
        f_init_deg<<<gn, BLOCK, 0, stream>>>(dis, n);
        f_deg<<<ge, BLOCK, 0, stream>>>(col, dis, e);
        f_dis_self<<<gn, BLOCK, 0, stream>>>(x, dis, s, n);
        f_agg1<<<ge, BLOCK, 0, stream>>>(row, col, dis, x, s, e);
        f_mlp<<<gn, BLOCK, 0, stream>>>(s, dis, W1, b1, W2, b2, h2, out, n);
        f_agg2<<<ge, BLOCK, 0, stream>>>(row, col, dis, h2, out, e);
        return;
    }

    int*    P      = (int*)d_ws;
    int*    H      = P + e;
    int*    totals = H + M;
    int*    tscan  = totals + 1024;
    float*  dis    = (float*)(tscan + 1024);
    float*  t      = dis + n;
    float2* u      = (float2*)(t + n);

    k_hist   <<<NB, 256, 0, stream>>>(col, H, e, NK);
    k_scanA  <<<GS, 1024, 0, stream>>>(H, totals, M);
    k_scanB  <<<1, 1024, 0, stream>>>(totals, tscan, GS);
    k_scanC  <<<GS, 1024, 0, stream>>>(H, tscan, M);
    k_scatter<<<NB, 256, 0, stream>>>(row, col, H, P, e, NK);
    k_degprep<<<NK, 256, 0, stream>>>(P, H, x, dis, t, n, e, NK);
    k_agg1mlp<<<NK, 256, 0, stream>>>(P, H, dis, t, W1, b1, W2, u, n, e, NK);
    k_agg2out<<<NK, 256, 0, stream>>>(P, H, dis, u, b2, (float2*)out, n, e, NK);
}

// Round 4
// 341.403 us; speedup vs baseline: 4.0220x; 1.0340x over previous
//
#include <hip/hip_runtime.h>

// GCN 2-layer, dims 1 -> 16 -> 2, N=100K, E=6.4M.
//
// R1: fabric float atomics = 32B packet each (~20 G/s) -> 1373 us.
// R2: LDS range-privatization kills atomics, pays 16x edge re-read -> 641 us.
// R3: full counting sort into 782 buckets: scatter writes 4B at random
//     cursors -> WRITE_SIZE 143MB (5.6x amplification), 353 us.
// R4: coarse buckets of CW=4096 nodes (NC=25). One tile-staged partition
//     pass with LDS-ordered flush (coalesced ~82-dword runs). Agg passes
//     keep a WHOLE coarse bucket's bins in LDS (16/16/32 KB), chunked over
//     C blocks with plain coalesced partial flushes + tiny node reduces.
//
// Algebra: dis = rsqrt(1+indeg); t = dis*x
//   s[c]  = dis[c]*(sum_{e->c} t[row] + t[c])
//   u[c]  = dis[c]*(W2 @ relu(s[c]*W1 + b1))          (float2)
//   out[c]= b2 + dis[c]*(sum_{e->c} u[row] + u[c])

static constexpr int CSH = 12;            // log2 coarse width
static constexpr int CW  = 1 << CSH;      // 4096 nodes / coarse bucket
static constexpr int MAXNC = 32;          // supports n <= 131072 (row<<12 fits 29b)
static constexpr int NB1 = 512;           // partition blocks
static constexpr int TIL = 2048;          // edges per scatter tile
static constexpr int BT  = 512;           // agg block threads

__device__ __forceinline__ int chunk_of(int e) {
    return ((e + NB1 * 4 - 1) / (NB1 * 4)) * 4;   // 4-aligned per-block chunk
}

// ---- 1) per-block coarse histogram: H[k*NB1 + b] ----
__global__ __launch_bounds__(256) void k_hist(const int* __restrict__ col,
        int* __restrict__ H, int e, int NC) {
    __shared__ int h[8 * MAXNC];
    for (int j = threadIdx.x; j < 8 * MAXNC; j += 256) h[j] = 0;
    __syncthreads();
    const int rep = (threadIdx.x & 7) * MAXNC;
    const int chunk = chunk_of(e);
    const int lo = blockIdx.x * chunk, end = min(lo + chunk, e);
    for (int i0 = lo + threadIdx.x * 4; i0 < end; i0 += 1024) {
        if (i0 + 3 < end) {
            int4 c4 = *reinterpret_cast<const int4*>(col + i0);
            atomicAdd(&h[rep + (c4.x >> CSH)], 1);
            atomicAdd(&h[rep + (c4.y >> CSH)], 1);
            atomicAdd(&h[rep + (c4.z >> CSH)], 1);
            atomicAdd(&h[rep + (c4.w >> CSH)], 1);
        } else {
            for (int m = 0; m < 4 && i0 + m < end; ++m)
                atomicAdd(&h[rep + (col[i0 + m] >> CSH)], 1);
        }
    }
    __syncthreads();
    for (int k = threadIdx.x; k < NC; k += 256) {
        int s = 0;
        for (int r = 0; r < 8; ++r) s += h[r * MAXNC + k];
        H[k * NB1 + blockIdx.x] = s;
    }
}

// ---- 2) exclusive scan of H (M = NC*NB1 <= 16384), one block ----
__global__ __launch_bounds__(1024) void k_scan(int* __restrict__ H, int M) {
    __shared__ int s[1024];
    const int tid = threadIdx.x;
    int loc[16];
    int sum = 0;
#pragma unroll
    for (int j = 0; j < 16; ++j) {
        int idx = tid * 16 + j;
        int v = (idx < M) ? H[idx] : 0;
        loc[j] = sum;
        sum += v;
    }
    s[tid] = sum;
    __syncthreads();
    for (int off = 1; off < 1024; off <<= 1) {
        int tv = (tid >= off) ? s[tid - off] : 0;
        __syncthreads();
        s[tid] += tv;
        __syncthreads();
    }
    int offs = (tid == 0) ? 0 : s[tid - 1];
#pragma unroll
    for (int j = 0; j < 16; ++j) {
        int idx = tid * 16 + j;
        if (idx < M) H[idx] = offs + loc[j];
    }
}

// ---- 3) tile-staged scatter: pack (row<<12 | col&4095), coalesced flush ----
__global__ __launch_bounds__(256) void k_scatter(const int* __restrict__ row,
        const int* __restrict__ col, const int* __restrict__ H,
        int* __restrict__ P1, int e, int NC) {
    __shared__ int cur[MAXNC];
    __shared__ int cnt[MAXNC];
    __shared__ int segs[MAXNC + 1];
    __shared__ int buf[TIL];
    __shared__ int dbuf[TIL];
    const int b = blockIdx.x;
    if (threadIdx.x < NC) cur[threadIdx.x] = H[threadIdx.x * NB1 + b];
    const int chunk = chunk_of(e);
    const int lo = b * chunk, end = min(lo + chunk, e);
    for (int t0 = lo; t0 < end; t0 += TIL) {
        if (threadIdx.x < NC) cnt[threadIdx.x] = 0;
        __syncthreads();
        int vk[8], vs[8], vp[8];
        bool vv[8];
#pragma unroll
        for (int hf = 0; hf < 2; ++hf) {
            const int i0 = t0 + hf * 1024 + threadIdx.x * 4;
            const bool full = (i0 + 3 < end);
            int4 c4, r4;
            if (full) {
                c4 = *reinterpret_cast<const int4*>(col + i0);
                r4 = *reinterpret_cast<const int4*>(row + i0);
            }
            int ca[4] = {c4.x, c4.y, c4.z, c4.w};
            int ra[4] = {r4.x, r4.y, r4.z, r4.w};
#pragma unroll
            for (int m = 0; m < 4; ++m) {
                const int slot = hf * 4 + m;
                const int i = i0 + m;
                bool ok = i < end;
                int c = 0, r = 0;
                if (full) { c = ca[m]; r = ra[m]; }
                else if (ok) { c = col[i]; r = row[i]; }
                vv[slot] = ok;
                if (ok) {
                    int k = c >> CSH;
                    vk[slot] = k;
                    vs[slot] = atomicAdd(&cnt[k], 1);
                    vp[slot] = (r << CSH) | (c & (CW - 1));
                }
            }
        }
        __syncthreads();
        if (threadIdx.x == 0) {
            int a = 0;
            for (int k = 0; k < NC; ++k) { segs[k] = a; a += cnt[k]; }
            segs[NC] = a;
        }
        __syncthreads();
#pragma unroll
        for (int slot = 0; slot < 8; ++slot) {
            if (vv[slot]) {
                int li = segs[vk[slot]] + vs[slot];
                buf[li]  = vp[slot];
                dbuf[li] = cur[vk[slot]] + vs[slot];
            }
        }
        __syncthreads();
        const int tot = segs[NC];
        for (int j = threadIdx.x; j < tot; j += 256) P1[dbuf[j]] = buf[j];
        if (threadIdx.x < NC) cur[threadIdx.x] += cnt[threadIdx.x];
        __syncthreads();
    }
}

// ---- 4) degree: whole coarse bucket binned in LDS, chunked partials ----
__global__ __launch_bounds__(BT) void k_deg(const int* __restrict__ P1,
        const int* __restrict__ H, int* __restrict__ Pd, int e, int NC, int C) {
    __shared__ int bin[CW];
    const int k = blockIdx.x / C, j = blockIdx.x % C;
    for (int q = threadIdx.x; q < CW; q += BT) bin[q] = 0;
    __syncthreads();
    const int s0 = H[k * NB1];
    const int s1 = (k + 1 < NC) ? H[(k + 1) * NB1] : e;
    const int ch = (s1 - s0 + C - 1) / C;
    const int lo = s0 + j * ch, hi = min(lo + ch, s1);
    for (int i = lo + threadIdx.x; i < hi; i += BT)
        atomicAdd(&bin[P1[i] & (CW - 1)], 1);
    __syncthreads();
    int* o = Pd + ((size_t)k * C + j) * CW;
    for (int q = threadIdx.x; q < CW; q += BT) o[q] = bin[q];
}

__global__ void k_prep(const int* __restrict__ Pd, const float* __restrict__ x,
        float* __restrict__ dis, float* __restrict__ t, int n, int C) {
    int c = blockIdx.x * blockDim.x + threadIdx.x;
    if (c >= n) return;
    int k = c >> CSH, l = c & (CW - 1);
    int d = 1;
    for (int j = 0; j < C; ++j) d += Pd[((size_t)k * C + j) * CW + l];
    float di = rsqrtf((float)d);
    dis[c] = di;
    t[c] = di * x[c];
}

// ---- 5) layer-1 aggregate ----
__global__ __launch_bounds__(BT) void k_agg1(const int* __restrict__ P1,
        const int* __restrict__ H, const float* __restrict__ t,
        float* __restrict__ Pf, int e, int NC, int C) {
    __shared__ float bin[CW];
    const int k = blockIdx.x / C, j = blockIdx.x % C;
    for (int q = threadIdx.x; q < CW; q += BT) bin[q] = 0.0f;
    __syncthreads();
    const int s0 = H[k * NB1];
    const int s1 = (k + 1 < NC) ? H[(k + 1) * NB1] : e;
    const int ch = (s1 - s0 + C - 1) / C;
    const int lo = s0 + j * ch, hi = min(lo + ch, s1);
    for (int i = lo + threadIdx.x; i < hi; i += BT) {
        int p = P1[i];
        atomicAdd(&bin[p & (CW - 1)], t[p >> CSH]);
    }
    __syncthreads();
    float* o = Pf + ((size_t)k * C + j) * CW;
    for (int q = threadIdx.x; q < CW; q += BT) o[q] = bin[q];
}

__global__ void k_mlp(const float* __restrict__ Pf, const float* __restrict__ dis,
        const float* __restrict__ t, const float* __restrict__ W1,
        const float* __restrict__ b1, const float* __restrict__ W2,
        float2* __restrict__ u, int n, int C) {
    int c = blockIdx.x * blockDim.x + threadIdx.x;
    if (c >= n) return;
    int k = c >> CSH, l = c & (CW - 1);
    float S = 0.0f;
    for (int j = 0; j < C; ++j) S += Pf[((size_t)k * C + j) * CW + l];
    float di = dis[c];
    float s = di * (S + t[c]);
    float a0 = 0.0f, a1 = 0.0f;
#pragma unroll
    for (int j = 0; j < 16; ++j) {
        float hh = fmaxf(fmaf(s, W1[j], b1[j]), 0.0f);
        a0 = fmaf(W2[j],      hh, a0);
        a1 = fmaf(W2[16 + j], hh, a1);
    }
    u[c] = make_float2(di * a0, di * a1);
}

// ---- 6) layer-2 aggregate (float2 bins, split x/y for bank spread) ----
__global__ __launch_bounds__(BT) void k_agg2(const int* __restrict__ P1,
        const int* __restrict__ H, const float2* __restrict__ u,
        float2* __restrict__ Pf2, int e, int NC, int C) {
    __shared__ float binx[CW];
    __shared__ float biny[CW];
    const int k = blockIdx.x / C, j = blockIdx.x % C;
    for (int q = threadIdx.x; q < CW; q += BT) { binx[q] = 0.0f; biny[q] = 0.0f; }
    __syncthreads();
    const int s0 = H[k * NB1];
    const int s1 = (k + 1 < NC) ? H[(k + 1) * NB1] : e;
    const int ch = (s1 - s0 + C - 1) / C;
    const int lo = s0 + j * ch, hi = min(lo + ch, s1);
    for (int i = lo + threadIdx.x; i < hi; i += BT) {
        int p = P1[i];
        float2 uv = u[p >> CSH];
        int l = p & (CW - 1);
        atomicAdd(&binx[l], uv.x);
        atomicAdd(&biny[l], uv.y);
    }
    __syncthreads();
    float2* o = Pf2 + ((size_t)k * C + j) * CW;
    for (int q = threadIdx.x; q < CW; q += BT) o[q] = make_float2(binx[q], biny[q]);
}

__global__ void k_out(const float2* __restrict__ Pf2, const float* __restrict__ dis,
        const float2* __restrict__ u, const float* __restrict__ b2,
        float2* __restrict__ out, int n, int C) {
    int c = blockIdx.x * blockDim.x + threadIdx.x;
    if (c >= n) return;
    int k = c >> CSH, l = c & (CW - 1);
    float sx = 0.0f, sy = 0.0f;
    for (int j = 0; j < C; ++j) {
        float2 v = Pf2[((size_t)k * C + j) * CW + l];
        sx += v.x; sy += v.y;
    }
    float di = dis[c];
    float2 uc = u[c];
    out[c] = make_float2(b2[0] + di * (sx + uc.x), b2[1] + di * (sy + uc.y));
}

// ---------- generic atomic fallback (any n/e, slow but correct) ----------
__global__ void f_init_deg(float* deg, int n) {
    int i = blockIdx.x * blockDim.x + threadIdx.x;
    if (i < n) deg[i] = 1.0f;
}
__global__ void f_deg(const int* col, float* deg, int e) {
    int i = blockIdx.x * blockDim.x + threadIdx.x;
    if (i < e) atomicAdd(&deg[col[i]], 1.0f);
}
__global__ void f_dis_self(const float* x, float* deg_dis, float* s, int n) {
    int i = blockIdx.x * blockDim.x + threadIdx.x;
    if (i < n) { float di = rsqrtf(deg_dis[i]); deg_dis[i] = di; s[i] = di * di * x[i]; }
}
__global__ void f_agg1(const int* row, const int* col, const float* dis,
                       const float* x, float* s, int e) {
    int i = blockIdx.x * blockDim.x + threadIdx.x;
    if (i < e) { int r = row[i], c = col[i]; atomicAdd(&s[c], dis[r] * dis[c] * x[r]); }
}
__global__ void f_mlp(const float* s, const float* dis, const float* W1,
                      const float* b1, const float* W2, const float* b2,
                      float* h2, float* out, int n) {
    int i = blockIdx.x * blockDim.x + threadIdx.x;
    if (i < n) {
        float sv = s[i], a0 = 0.0f, a1 = 0.0f;
#pragma unroll
        for (int j = 0; j < 16; ++j) {
            float h1 = fmaxf(sv * W1[j] + b1[j], 0.0f);
            a0 = fmaf(W2[j], h1, a0); a1 = fmaf(W2[16 + j], h1, a1);
        }
        h2[2 * i] = a0; h2[2 * i + 1] = a1;
        float d2 = dis[i] * dis[i];
        out[2 * i] = b2[0] + d2 * a0; out[2 * i + 1] = b2[1] + d2 * a1;
    }
}
__global__ void f_agg2(const int* row, const int* col, const float* dis,
                       const float* h2, float* out, int e) {
    int i = blockIdx.x * blockDim.x + threadIdx.x;
    if (i < e) {
        int r = row[i], c = col[i];
        float nm = dis[r] * dis[c];
        float2 hv = *reinterpret_cast<const float2*>(&h2[2 * r]);
        atomicAdd(&out[2 * c], nm * hv.x);
        atomicAdd(&out[2 * c + 1], nm * hv.y);
    }
}
// -------------------------------------------------------------------------

extern "C" void kernel_launch(void* const* d_in, const int* in_sizes, int n_in,
                              void* d_out, int out_size, void* d_ws, size_t ws_size,
                              hipStream_t stream) {
    const float* x  = (const float*)d_in[0];
    const int*   ei = (const int*)d_in[1];
    const float* W1 = (const float*)d_in[2];
    const float* b1 = (const float*)d_in[3];
    const float* W2 = (const float*)d_in[4];
    const float* b2 = (const float*)d_in[5];

    const int n = in_sizes[0];
    const int e = in_sizes[1] / 2;
    const int* row = ei;
    const int* col = ei + e;

    const int NC = (n + CW - 1) >> CSH;

    // ws (4B units): P1[e] | H[MAXNC*NB1] | dis[n] | t[n] | u[2n] | partials
    size_t base4 = (size_t)e + (size_t)MAXNC * NB1 + 4ull * (size_t)n;
    int C = 12;
    while (C >= 2 && (base4 + (size_t)NC * C * CW * 2) * 4 > ws_size) --C;

    if (n > 131072 || NC > MAXNC || C < 2) {
        float* dis = (float*)d_ws; float* s = dis + n; float* h2 = s + n;
        const int gn = (n + 255) / 256, ge = (e + 255) / 256;
        f_init_deg<<<gn, 256, 0, stream>>>(dis, n);
        f_deg<<<ge, 256, 0, stream>>>(col, dis, e);
        f_dis_self<<<gn, 256, 0, stream>>>(x, dis, s, n);
        f_agg1<<<ge, 256, 0, stream>>>(row, col, dis, x, s, e);
        f_mlp<<<gn, 256, 0, stream>>>(s, dis, W1, b1, W2, b2, h2, (float*)d_out, n);
        f_agg2<<<ge, 256, 0, stream>>>(row, col, dis, h2, (float*)d_out, e);
        return;
    }

    int*    P1  = (int*)d_ws;
    int*    H   = P1 + e;
    float*  dis = (float*)(H + MAXNC * NB1);
    float*  t   = dis + n;
    float2* u   = (float2*)(t + n);
    void*   Pp  = (void*)(u + n);   // partials, reused int/float/float2

    const int gn = (n + 255) / 256;

    k_hist   <<<NB1, 256, 0, stream>>>(col, H, e, NC);
    k_scan   <<<1, 1024, 0, stream>>>(H, NC * NB1);
    k_scatter<<<NB1, 256, 0, stream>>>(row, col, H, P1, e, NC);
    k_deg    <<<NC * C, BT, 0, stream>>>(P1, H, (int*)Pp, e, NC, C);
    k_prep   <<<gn, 256, 0, stream>>>((const int*)Pp, x, dis, t, n, C);
    k_agg1   <<<NC * C, BT, 0, stream>>>(P1, H, t, (float*)Pp, e, NC, C);
    k_mlp    <<<gn, 256, 0, stream>>>((const float*)Pp, dis, t, W1, b1, W2, u, n, C);
    k_agg2   <<<NC * C, BT, 0, stream>>>(P1, H, u, (float2*)Pp, e, NC, C);
    k_out    <<<gn, 256, 0, stream>>>((const float2*)Pp, dis, u, b2, (float2*)d_out, n, C);
}

// Round 5
// 317.360 us; speedup vs baseline: 4.3267x; 1.0758x over previous
//
#include <hip/hip_runtime.h>

// GCN 2-layer, dims 1 -> 16 -> 2, N=100K, E=6.4M.
//
// R1: fabric float atomics (~20 G/s) -> 1373 us.
// R2: LDS range-privatization, 16x edge re-read -> 641 us.
// R3: fine counting sort, 4B random scatter writes (143MB WRITE) -> 353 us.
// R4: coarse buckets + LDS bins + chunk partials -> 341 us, BUT counters
//     showed agg kernels at 15% occupancy / 2.8% HBM / 1.2% VALU: the ws
//     budget shrank the chunk count C -> grid ~150 blocks; serial dependent
//     chains (stream load -> gather -> LDS atomic) left CUs idle.
// R5: latency attack: CW=2048 (NC=49, 8KB bins), scalar-only partials
//     (agg2 split into x/y passes over SoA ux/uy) so C fits ws at ~18-28
//     -> grid ~900-1400 blocks; ILP-4 unroll (4 chains in flight/thread).
//
// Algebra: dis = rsqrt(1+indeg); t = dis*x
//   s[c]  = dis[c]*(sum_{e->c} t[row] + t[c])
//   (a0,a1)[c] = W2 @ relu(s[c]*W1 + b1);  ux/uy[c] = dis[c]*a{0,1}[c]
//   out[2c+w] = b2[w] + dis[c]*(sum_{e->c} u_w[row] + u_w[c])

static constexpr int CSH   = 11;           // log2 coarse width
static constexpr int CW    = 1 << CSH;     // 2048 nodes / bucket
static constexpr int MAXNC = 64;           // n <= 131072 (row<<11 fits 28b)
static constexpr int NB1   = 512;          // partition blocks
static constexpr int TIL   = 2048;         // edges per scatter tile

__device__ __forceinline__ int chunk_of(int e) {
    return ((e + NB1 * 4 - 1) / (NB1 * 4)) * 4;   // 4-aligned per-block chunk
}

// ---- 1) per-block coarse histogram: H[k*NB1 + b] ----
__global__ __launch_bounds__(256) void k_hist(const int* __restrict__ col,
        int* __restrict__ H, int e, int NC) {
    __shared__ int h[8 * MAXNC];
    for (int j = threadIdx.x; j < 8 * MAXNC; j += 256) h[j] = 0;
    __syncthreads();
    const int rep = (threadIdx.x & 7) * MAXNC;
    const int chunk = chunk_of(e);
    const int lo = blockIdx.x * chunk, end = min(lo + chunk, e);
    for (int i0 = lo + threadIdx.x * 4; i0 < end; i0 += 1024) {
        if (i0 + 3 < end) {
            int4 c4 = *reinterpret_cast<const int4*>(col + i0);
            atomicAdd(&h[rep + (c4.x >> CSH)], 1);
            atomicAdd(&h[rep + (c4.y >> CSH)], 1);
            atomicAdd(&h[rep + (c4.z >> CSH)], 1);
            atomicAdd(&h[rep + (c4.w >> CSH)], 1);
        } else {
            for (int m = 0; m < 4 && i0 + m < end; ++m)
                atomicAdd(&h[rep + (col[i0 + m] >> CSH)], 1);
        }
    }
    __syncthreads();
    for (int k = threadIdx.x; k < NC; k += 256) {
        int s = 0;
        for (int r = 0; r < 8; ++r) s += h[r * MAXNC + k];
        H[k * NB1 + blockIdx.x] = s;
    }
}

// ---- 2) exclusive scan of H (M = NC*NB1 <= 32768), one block ----
__global__ __launch_bounds__(1024) void k_scan(int* __restrict__ H, int M) {
    __shared__ int s[1024];
    const int tid = threadIdx.x;
    int loc[32];
    int sum = 0;
#pragma unroll
    for (int j = 0; j < 32; ++j) {
        int idx = tid * 32 + j;
        int v = (idx < M) ? H[idx] : 0;
        loc[j] = sum;
        sum += v;
    }
    s[tid] = sum;
    __syncthreads();
    for (int off = 1; off < 1024; off <<= 1) {
        int tv = (tid >= off) ? s[tid - off] : 0;
        __syncthreads();
        s[tid] += tv;
        __syncthreads();
    }
    int offs = (tid == 0) ? 0 : s[tid - 1];
#pragma unroll
    for (int j = 0; j < 32; ++j) {
        int idx = tid * 32 + j;
        if (idx < M) H[idx] = offs + loc[j];
    }
}

// ---- 3) tile-staged scatter: pack (row<<11 | col&2047), coalesced flush ----
__global__ __launch_bounds__(256) void k_scatter(const int* __restrict__ row,
        const int* __restrict__ col, const int* __restrict__ H,
        int* __restrict__ P1, int e, int NC) {
    __shared__ int cur[MAXNC];
    __shared__ int cnt[MAXNC];
    __shared__ int segs[MAXNC + 1];
    __shared__ int buf[TIL];
    __shared__ int dbuf[TIL];
    const int b = blockIdx.x;
    if (threadIdx.x < NC) cur[threadIdx.x] = H[threadIdx.x * NB1 + b];
    const int chunk = chunk_of(e);
    const int lo = b * chunk, end = min(lo + chunk, e);
    for (int t0 = lo; t0 < end; t0 += TIL) {
        if (threadIdx.x < NC) cnt[threadIdx.x] = 0;
        __syncthreads();
        int vk[8], vs[8], vp[8];
        bool vv[8];
#pragma unroll
        for (int hf = 0; hf < 2; ++hf) {
            const int i0 = t0 + hf * 1024 + threadIdx.x * 4;
            const bool full = (i0 + 3 < end);
            int4 c4, r4;
            if (full) {
                c4 = *reinterpret_cast<const int4*>(col + i0);
                r4 = *reinterpret_cast<const int4*>(row + i0);
            }
            int ca[4] = {c4.x, c4.y, c4.z, c4.w};
            int ra[4] = {r4.x, r4.y, r4.z, r4.w};
#pragma unroll
            for (int m = 0; m < 4; ++m) {
                const int slot = hf * 4 + m;
                const int i = i0 + m;
                bool ok = i < end;
                int c = 0, r = 0;
                if (full) { c = ca[m]; r = ra[m]; }
                else if (ok) { c = col[i]; r = row[i]; }
                vv[slot] = ok;
                if (ok) {
                    int k = c >> CSH;
                    vk[slot] = k;
                    vs[slot] = atomicAdd(&cnt[k], 1);
                    vp[slot] = (r << CSH) | (c & (CW - 1));
                }
            }
        }
        __syncthreads();
        if (threadIdx.x == 0) {
            int a = 0;
            for (int k = 0; k < NC; ++k) { segs[k] = a; a += cnt[k]; }
            segs[NC] = a;
        }
        __syncthreads();
#pragma unroll
        for (int slot = 0; slot < 8; ++slot) {
            if (vv[slot]) {
                int li = segs[vk[slot]] + vs[slot];
                buf[li]  = vp[slot];
                dbuf[li] = cur[vk[slot]] + vs[slot];
            }
        }
        __syncthreads();
        const int tot = segs[NC];
        for (int j = threadIdx.x; j < tot; j += 256) P1[dbuf[j]] = buf[j];
        if (threadIdx.x < NC) cur[threadIdx.x] += cnt[threadIdx.x];
        __syncthreads();
    }
}

// ---- 4) degree pass: LDS int bins, ILP-4, chunk partials ----
__global__ __launch_bounds__(256) void k_deg(const int* __restrict__ P1,
        const int* __restrict__ H, int* __restrict__ Pd, int e, int NC, int C) {
    __shared__ int bin[CW];
    const int k = blockIdx.x / C, j = blockIdx.x % C;
    for (int q = threadIdx.x; q < CW; q += 256) bin[q] = 0;
    __syncthreads();
    const int s0 = H[k * NB1];
    const int s1 = (k + 1 < NC) ? H[(k + 1) * NB1] : e;
    const int ch = (s1 - s0 + C - 1) / C;
    const int lo = s0 + j * ch, hi = min(lo + ch, s1);
    int i = lo + threadIdx.x;
    for (; i + 768 < hi; i += 1024) {
        int p0 = P1[i], p1 = P1[i + 256], p2 = P1[i + 512], p3 = P1[i + 768];
        atomicAdd(&bin[p0 & (CW - 1)], 1);
        atomicAdd(&bin[p1 & (CW - 1)], 1);
        atomicAdd(&bin[p2 & (CW - 1)], 1);
        atomicAdd(&bin[p3 & (CW - 1)], 1);
    }
    for (; i < hi; i += 256) atomicAdd(&bin[P1[i] & (CW - 1)], 1);
    __syncthreads();
    int* o = Pd + ((size_t)k * C + j) * CW;
    for (int q = threadIdx.x; q < CW; q += 256) o[q] = bin[q];
}

// ---- 5) generic scalar gather-aggregate: bin[col] += src[row], ILP-4 ----
__global__ __launch_bounds__(256) void k_aggf(const int* __restrict__ P1,
        const int* __restrict__ H, const float* __restrict__ src,
        float* __restrict__ Pf, int e, int NC, int C) {
    __shared__ float bin[CW];
    const int k = blockIdx.x / C, j = blockIdx.x % C;
    for (int q = threadIdx.x; q < CW; q += 256) bin[q] = 0.0f;
    __syncthreads();
    const int s0 = H[k * NB1];
    const int s1 = (k + 1 < NC) ? H[(k + 1) * NB1] : e;
    const int ch = (s1 - s0 + C - 1) / C;
    const int lo = s0 + j * ch, hi = min(lo + ch, s1);
    int i = lo + threadIdx.x;
    for (; i + 768 < hi; i += 1024) {
        int p0 = P1[i], p1 = P1[i + 256], p2 = P1[i + 512], p3 = P1[i + 768];
        float v0 = src[p0 >> CSH], v1 = src[p1 >> CSH];
        float v2 = src[p2 >> CSH], v3 = src[p3 >> CSH];
        atomicAdd(&bin[p0 & (CW - 1)], v0);
        atomicAdd(&bin[p1 & (CW - 1)], v1);
        atomicAdd(&bin[p2 & (CW - 1)], v2);
        atomicAdd(&bin[p3 & (CW - 1)], v3);
    }
    for (; i < hi; i += 256) {
        int p = P1[i];
        atomicAdd(&bin[p & (CW - 1)], src[p >> CSH]);
    }
    __syncthreads();
    float* o = Pf + ((size_t)k * C + j) * CW;
    for (int q = threadIdx.x; q < CW; q += 256) o[q] = bin[q];
}

// ---- 6) node kernels ----
__global__ void k_prep(const int* __restrict__ Pd, const float* __restrict__ x,
        float* __restrict__ dis, float* __restrict__ t, int n, int C) {
    int c = blockIdx.x * blockDim.x + threadIdx.x;
    if (c >= n) return;
    int k = c >> CSH, l = c & (CW - 1);
    int d = 1;
    for (int j = 0; j < C; ++j) d += Pd[((size_t)k * C + j) * CW + l];
    float di = rsqrtf((float)d);
    dis[c] = di;
    t[c] = di * x[c];
}

__global__ void k_mlp(const float* __restrict__ Pf, const float* __restrict__ dis,
        const float* __restrict__ t, const float* __restrict__ W1,
        const float* __restrict__ b1, const float* __restrict__ W2,
        float* __restrict__ ux, float* __restrict__ uy, int n, int C) {
    int c = blockIdx.x * blockDim.x + threadIdx.x;
    if (c >= n) return;
    int k = c >> CSH, l = c & (CW - 1);
    float S = 0.0f;
    for (int j = 0; j < C; ++j) S += Pf[((size_t)k * C + j) * CW + l];
    float di = dis[c];
    float s = di * (S + t[c]);
    float a0 = 0.0f, a1 = 0.0f;
#pragma unroll
    for (int j = 0; j < 16; ++j) {
        float hh = fmaxf(fmaf(s, W1[j], b1[j]), 0.0f);
        a0 = fmaf(W2[j],      hh, a0);
        a1 = fmaf(W2[16 + j], hh, a1);
    }
    ux[c] = di * a0;
    uy[c] = di * a1;
}

// out[2c+w] = b2[w] + dis[c]*(sum partials + u_w[c])
__global__ void k_outp(const float* __restrict__ Pf, const float* __restrict__ dis,
        const float* __restrict__ uw, const float* __restrict__ b2,
        float* __restrict__ out, int n, int C, int w) {
    int c = blockIdx.x * blockDim.x + threadIdx.x;
    if (c >= n) return;
    int k = c >> CSH, l = c & (CW - 1);
    float S = 0.0f;
    for (int j = 0; j < C; ++j) S += Pf[((size_t)k * C + j) * CW + l];
    out[2 * c + w] = b2[w] + dis[c] * (S + uw[c]);
}

// ---------- generic atomic fallback (any n/e, slow but correct) ----------
__global__ void f_init_deg(float* deg, int n) {
    int i = blockIdx.x * blockDim.x + threadIdx.x;
    if (i < n) deg[i] = 1.0f;
}
__global__ void f_deg(const int* col, float* deg, int e) {
    int i = blockIdx.x * blockDim.x + threadIdx.x;
    if (i < e) atomicAdd(&deg[col[i]], 1.0f);
}
__global__ void f_dis_self(const float* x, float* deg_dis, float* s, int n) {
    int i = blockIdx.x * blockDim.x + threadIdx.x;
    if (i < n) { float di = rsqrtf(deg_dis[i]); deg_dis[i] = di; s[i] = di * di * x[i]; }
}
__global__ void f_agg1(const int* row, const int* col, const float* dis,
                       const float* x, float* s, int e) {
    int i = blockIdx.x * blockDim.x + threadIdx.x;
    if (i < e) { int r = row[i], c = col[i]; atomicAdd(&s[c], dis[r] * dis[c] * x[r]); }
}
__global__ void f_mlp(const float* s, const float* dis, const float* W1,
                      const float* b1, const float* W2, const float* b2,
                      float* h2, float* out, int n) {
    int i = blockIdx.x * blockDim.x + threadIdx.x;
    if (i < n) {
        float sv = s[i], a0 = 0.0f, a1 = 0.0f;
#pragma unroll
        for (int j = 0; j < 16; ++j) {
            float h1 = fmaxf(sv * W1[j] + b1[j], 0.0f);
            a0 = fmaf(W2[j], h1, a0); a1 = fmaf(W2[16 + j], h1, a1);
        }
        h2[2 * i] = a0; h2[2 * i + 1] = a1;
        float d2 = dis[i] * dis[i];
        out[2 * i] = b2[0] + d2 * a0; out[2 * i + 1] = b2[1] + d2 * a1;
    }
}
__global__ void f_agg2(const int* row, const int* col, const float* dis,
                       const float* h2, float* out, int e) {
    int i = blockIdx.x * blockDim.x + threadIdx.x;
    if (i < e) {
        int r = row[i], c = col[i];
        float nm = dis[r] * dis[c];
        float2 hv = *reinterpret_cast<const float2*>(&h2[2 * r]);
        atomicAdd(&out[2 * c], nm * hv.x);
        atomicAdd(&out[2 * c + 1], nm * hv.y);
    }
}
// -------------------------------------------------------------------------

extern "C" void kernel_launch(void* const* d_in, const int* in_sizes, int n_in,
                              void* d_out, int out_size, void* d_ws, size_t ws_size,
                              hipStream_t stream) {
    const float* x  = (const float*)d_in[0];
    const int*   ei = (const int*)d_in[1];
    const float* W1 = (const float*)d_in[2];
    const float* b1 = (const float*)d_in[3];
    const float* W2 = (const float*)d_in[4];
    const float* b2 = (const float*)d_in[5];

    const int n = in_sizes[0];
    const int e = in_sizes[1] / 2;
    const int* row = ei;
    const int* col = ei + e;

    const int NC = (n + CW - 1) >> CSH;

    // ws (4B units): P1[e] | H[MAXNC*NB1] | dis[n] | t[n] | ux[n] | uy[n] | Pp[NC*C*CW]
    const size_t ws4   = ws_size / 4;
    const size_t base4 = (size_t)e + (size_t)MAXNC * NB1 + 4ull * (size_t)n;
    int C = 32;
    while (C >= 2 && base4 + (size_t)NC * C * CW > ws4) --C;

    if (NC > MAXNC || C < 2) {
        float* dis = (float*)d_ws; float* s = dis + n; float* h2 = s + n;
        const int gn = (n + 255) / 256, ge = (e + 255) / 256;
        f_init_deg<<<gn, 256, 0, stream>>>(dis, n);
        f_deg<<<ge, 256, 0, stream>>>(col, dis, e);
        f_dis_self<<<gn, 256, 0, stream>>>(x, dis, s, n);
        f_agg1<<<ge, 256, 0, stream>>>(row, col, dis, x, s, e);
        f_mlp<<<gn, 256, 0, stream>>>(s, dis, W1, b1, W2, b2, h2, (float*)d_out, n);
        f_agg2<<<ge, 256, 0, stream>>>(row, col, dis, h2, (float*)d_out, e);
        return;
    }

    int*   P1  = (int*)d_ws;
    int*   H   = P1 + e;
    float* dis = (float*)(H + MAXNC * NB1);
    float* t   = dis + n;
    float* ux  = t + n;
    float* uy  = ux + n;
    float* Pp  = uy + n;   // partials, reused int/float per stage

    const int gn = (n + 255) / 256;
    const int ga = NC * C;

    k_hist   <<<NB1, 256, 0, stream>>>(col, H, e, NC);
    k_scan   <<<1, 1024, 0, stream>>>(H, NC * NB1);
    k_scatter<<<NB1, 256, 0, stream>>>(row, col, H, P1, e, NC);
    k_deg    <<<ga, 256, 0, stream>>>(P1, H, (int*)Pp, e, NC, C);
    k_prep   <<<gn, 256, 0, stream>>>((const int*)Pp, x, dis, t, n, C);
    k_aggf   <<<ga, 256, 0, stream>>>(P1, H, t, Pp, e, NC, C);
    k_mlp    <<<gn, 256, 0, stream>>>(Pp, dis, t, W1, b1, W2, ux, uy, n, C);
    k_aggf   <<<ga, 256, 0, stream>>>(P1, H, ux, Pp, e, NC, C);
    k_outp   <<<gn, 256, 0, stream>>>(Pp, dis, ux, b2, (float*)d_out, n, C, 0);
    k_aggf   <<<ga, 256, 0, stream>>>(P1, H, uy, Pp, e, NC, C);
    k_outp   <<<gn, 256, 0, stream>>>(Pp, dis, uy, b2, (float*)d_out, n, C, 1);
}